// Round 3
// baseline (486.744 us; speedup 1.0000x reference)
//
#include <hip/hip_runtime.h>

#define EPSN 1e-8f

typedef _Float16 half8 __attribute__((ext_vector_type(8)));
typedef _Float16 half4 __attribute__((ext_vector_type(4)));
typedef __fp16 fp16x2 __attribute__((ext_vector_type(2)));   // cvt_pkrtz result type
typedef float floatx4 __attribute__((ext_vector_type(4)));

// lgkmcnt-only barrier: orders LDS across the workgroup without draining vmcnt.
#define LDS_BARRIER()                                              \
    do {                                                           \
        asm volatile("s_waitcnt lgkmcnt(0)" ::: "memory");         \
        __builtin_amdgcn_s_barrier();                              \
        asm volatile("" ::: "memory");                             \
    } while (0)

// ---------------- K1: vis inverse norms (wave per row) ----------------
__global__ __launch_bounds__(256) void k_vinv(const float* __restrict__ vis,
                                              float* __restrict__ vinv) {
    int row  = blockIdx.x * 4 + (threadIdx.x >> 6);   // 8192 rows total
    int lane = threadIdx.x & 63;
    const float4* src = reinterpret_cast<const float4*>(vis + (size_t)row * 512);
    float4 a = src[lane];
    float4 b = src[lane + 64];
    float s = a.x*a.x + a.y*a.y + a.z*a.z + a.w*a.w
            + b.x*b.x + b.y*b.y + b.z*b.z + b.w*b.w;
    #pragma unroll
    for (int off = 1; off < 64; off <<= 1) s += __shfl_xor(s, off);
    if (lane == 0) vinv[row] = 1.0f / fmaxf(sqrtf(s), EPSN);
}

// ---------------- K2: per-(b,p,tb,vq) GEMM + exp-sums ----------------
// WG: 256 threads / 4 waves in 2x2, WG tile 128v x 128t, wave tile 64x64.
//
// COALESCED STAGING (the round-3 change): thread t covers rows
// (t>>3)*4 + j (j=0..3) at k-slot (t&7)*4 floats. One load instruction's
// 64 lanes now cover 8 rows x 128 contiguous bytes = 16 fully-consumed
// cache lines, vs the old 2-threads-per-row map where every lane hit its
// own line (64 lines/inst, 4x redundant lookups). The kernel was
// TA/L1-request-bound (~524k line-req/CU ~= the 478k-cycle dispatch);
// this cuts requests 4x.
//
// LDS: rows are 64 B (32 halfs) with XOR slot swizzle
//   phys_16B_slot = slot ^ ((row>>1)&3)
// applied identically on the 8-B writes (slot=lk>>1, sub=(lk&1)*4 halfs)
// and the 16-B fragment reads (koff). Write pattern: each row-pair covers
// all 32 banks exactly once -> conflict-free minimum for b64.
#define LDA 32   // halfs per row = 64 B

__global__ __launch_bounds__(256, 3) void k_main(
    const float* __restrict__ vis, const float* __restrict__ text,
    const float* __restrict__ vinv,
    float* __restrict__ g_rowsum, float* __restrict__ g_colsum,
    float* __restrict__ g_dsum)
{
    __shared__ _Float16 Ash[128 * LDA];   // 8 KB
    __shared__ _Float16 Bsh[128 * LDA];   // 8 KB
    __shared__ float tn2[128];
    __shared__ float vinvS[128];
    __shared__ float rowS[128];
    __shared__ float colS[128];

    // ---- XCD swizzle: twins (same s>>2, same xcd, s&3=0..3) share text tile
    const int pid = blockIdx.x;
    const int xcd = pid & 7;
    const int s_  = pid >> 3;
    const int blk = (s_ & 3) + (xcd << 2) + ((s_ >> 2) << 5);   // bijection on 4096

    const int vq   = blk & 3;
    const int tb   = (blk >> 2) & 3;
    const int bp   = blk >> 4;            // b*16 + p
    const int p    = bp & 15;
    const int b    = bp >> 4;
    const int tid  = threadIdx.x;
    const int lane = tid & 63;
    const int wave = tid >> 6;
    const int wy   = wave >> 1;           // v-half of WG tile
    const int wx   = wave & 1;            // t-half of WG tile
    const int m15  = lane & 15;
    const int g4   = lane >> 4;

    if (tid < 128) {                      // ordered by first in-loop barrier
        rowS[tid] = 0.f; colS[tid] = 0.f;
        vinvS[tid] = vinv[b * 512 + vq * 128 + tid];
    }

    floatx4 acc[4][4];
    floatx4 zf = {0.f, 0.f, 0.f, 0.f};
    #pragma unroll
    for (int mb = 0; mb < 4; ++mb)
        #pragma unroll
        for (int nb = 0; nb < 4; ++nb) acc[mb][nb] = zf;

    // ---- staging map: 8 threads per row, 4 row-rounds
    const int lrow = tid >> 3;            // 0..31
    const int lk   = tid & 7;             // 16-B unit within the 32-float slice
    const int r0   = lrow * 4;            // rows r0..r0+3

    // swizzled LDS write offsets (halfs), constant per thread, one per j
    const int slot = lk >> 1;
    const int sub  = (lk & 1) * 4;
    const int wof0 = (r0 + 0) * LDA + (((slot) ^ (((r0 + 0) >> 1) & 3)) << 3) + sub;
    const int wof1 = (r0 + 1) * LDA + (((slot) ^ (((r0 + 1) >> 1) & 3)) << 3) + sub;
    const int wof2 = (r0 + 2) * LDA + (((slot) ^ (((r0 + 2) >> 1) & 3)) << 3) + sub;
    const int wof3 = (r0 + 3) * LDA + (((slot) ^ (((r0 + 3) >> 1) & 3)) << 3) + sub;
    // swizzled read k-offset (halfs), constant per thread
    const int koff = ((g4 ^ ((m15 >> 1) & 3)) << 3);

    const float* aP =
        vis + (size_t)b * 512 * 512 + (size_t)(vq * 128 + r0) * 512 + lk * 4;
    const float* bP0 =
        text + ((size_t)((b * 512 + tb * 128 + r0) * 16 + p)) * 512 + lk * 4;
    const float* bP1 = bP0 + 1 * 16 * 512;
    const float* bP2 = bP0 + 2 * 16 * 512;
    const float* bP3 = bP0 + 3 * 16 * 512;

    float t0 = 0.f, t1 = 0.f, t2 = 0.f, t3 = 0.f;   // text row-norm partials

    for (int kc = 0; kc < 16; ++kc) {
        // A rows r0..r0+3 (row stride 512 floats -> imm-foldable offsets)
        float4 a0 = *reinterpret_cast<const float4*>(aP);
        float4 a1 = *reinterpret_cast<const float4*>(aP + 512);
        float4 a2 = *reinterpret_cast<const float4*>(aP + 1024);
        float4 a3 = *reinterpret_cast<const float4*>(aP + 1536);
        float4 b0 = *reinterpret_cast<const float4*>(bP0);
        float4 b1 = *reinterpret_cast<const float4*>(bP1);
        float4 b2 = *reinterpret_cast<const float4*>(bP2);
        float4 b3 = *reinterpret_cast<const float4*>(bP3);
        aP += 32; bP0 += 32; bP1 += 32; bP2 += 32; bP3 += 32;

        {
            union { half4 v; fp16x2 q[2]; } u;
            u.q[0] = __builtin_amdgcn_cvt_pkrtz(a0.x, a0.y);
            u.q[1] = __builtin_amdgcn_cvt_pkrtz(a0.z, a0.w);
            *reinterpret_cast<half4*>(&Ash[wof0]) = u.v;
            u.q[0] = __builtin_amdgcn_cvt_pkrtz(a1.x, a1.y);
            u.q[1] = __builtin_amdgcn_cvt_pkrtz(a1.z, a1.w);
            *reinterpret_cast<half4*>(&Ash[wof1]) = u.v;
            u.q[0] = __builtin_amdgcn_cvt_pkrtz(a2.x, a2.y);
            u.q[1] = __builtin_amdgcn_cvt_pkrtz(a2.z, a2.w);
            *reinterpret_cast<half4*>(&Ash[wof2]) = u.v;
            u.q[0] = __builtin_amdgcn_cvt_pkrtz(a3.x, a3.y);
            u.q[1] = __builtin_amdgcn_cvt_pkrtz(a3.z, a3.w);
            *reinterpret_cast<half4*>(&Ash[wof3]) = u.v;
        }
        t0 += b0.x*b0.x + b0.y*b0.y + b0.z*b0.z + b0.w*b0.w;
        t1 += b1.x*b1.x + b1.y*b1.y + b1.z*b1.z + b1.w*b1.w;
        t2 += b2.x*b2.x + b2.y*b2.y + b2.z*b2.z + b2.w*b2.w;
        t3 += b3.x*b3.x + b3.y*b3.y + b3.z*b3.z + b3.w*b3.w;
        {
            union { half4 v; fp16x2 q[2]; } u;
            u.q[0] = __builtin_amdgcn_cvt_pkrtz(b0.x, b0.y);
            u.q[1] = __builtin_amdgcn_cvt_pkrtz(b0.z, b0.w);
            *reinterpret_cast<half4*>(&Bsh[wof0]) = u.v;
            u.q[0] = __builtin_amdgcn_cvt_pkrtz(b1.x, b1.y);
            u.q[1] = __builtin_amdgcn_cvt_pkrtz(b1.z, b1.w);
            *reinterpret_cast<half4*>(&Bsh[wof1]) = u.v;
            u.q[0] = __builtin_amdgcn_cvt_pkrtz(b2.x, b2.y);
            u.q[1] = __builtin_amdgcn_cvt_pkrtz(b2.z, b2.w);
            *reinterpret_cast<half4*>(&Bsh[wof2]) = u.v;
            u.q[0] = __builtin_amdgcn_cvt_pkrtz(b3.x, b3.y);
            u.q[1] = __builtin_amdgcn_cvt_pkrtz(b3.z, b3.w);
            *reinterpret_cast<half4*>(&Bsh[wof3]) = u.v;
        }
        LDS_BARRIER();
        // ---- MFMA: wave (wy,wx) covers rows [wy*64,+64) x cols [wx*64,+64) ----
        half8 af[4];
        #pragma unroll
        for (int mb = 0; mb < 4; ++mb)
            af[mb] = *reinterpret_cast<const half8*>(
                &Ash[(wy * 64 + mb * 16 + m15) * LDA + koff]);
        #pragma unroll
        for (int nb = 0; nb < 4; ++nb) {
            half8 bf = *reinterpret_cast<const half8*>(
                &Bsh[(wx * 64 + nb * 16 + m15) * LDA + koff]);
            #pragma unroll
            for (int mb = 0; mb < 4; ++mb)
                acc[mb][nb] = __builtin_amdgcn_mfma_f32_16x16x32_f16(
                    af[mb], bf, acc[mb][nb], 0, 0, 0);
        }
        LDS_BARRIER();   // reads of Ash/Bsh done before next chunk's writes
    }

    // text norms: reduce each row partial over the 8-lane k-group
    t0 += __shfl_xor(t0, 1); t0 += __shfl_xor(t0, 2); t0 += __shfl_xor(t0, 4);
    t1 += __shfl_xor(t1, 1); t1 += __shfl_xor(t1, 2); t1 += __shfl_xor(t1, 4);
    t2 += __shfl_xor(t2, 1); t2 += __shfl_xor(t2, 2); t2 += __shfl_xor(t2, 4);
    t3 += __shfl_xor(t3, 1); t3 += __shfl_xor(t3, 2); t3 += __shfl_xor(t3, 4);
    if (lk == 0) {
        tn2[r0 + 0] = 1.0f / fmaxf(sqrtf(t0), EPSN);
        tn2[r0 + 1] = 1.0f / fmaxf(sqrtf(t1), EPSN);
        tn2[r0 + 2] = 1.0f / fmaxf(sqrtf(t2), EPSN);
        tn2[r0 + 3] = 1.0f / fmaxf(sqrtf(t3), EPSN);
    }
    __syncthreads();

    float tinvc[4];
    #pragma unroll
    for (int nb = 0; nb < 4; ++nb) tinvc[nb] = tn2[wx * 64 + nb * 16 + m15];

    float colpart[4];
    #pragma unroll
    for (int nb = 0; nb < 4; ++nb) colpart[nb] = 0.f;
    float dsum = 0.f;

    // epilogue: scale, exp, row/col partial sums
    #pragma unroll
    for (int mb = 0; mb < 4; ++mb) {
        #pragma unroll
        for (int r = 0; r < 4; ++r) {
            int vloc  = wy * 64 + mb * 16 + g4 * 4 + r;      // C/D row mapping
            int vglob = vq * 128 + vloc;
            float vi  = vinvS[vloc];
            float rp  = 0.f;
            #pragma unroll
            for (int nb = 0; nb < 4; ++nb) {
                float sim  = acc[mb][nb][r] * vi * tinvc[nb];
                int tglob  = tb * 128 + wx * 64 + nb * 16 + m15;  // C/D col mapping
                if (vglob == tglob) dsum += sim;
                float e = __expf(sim);
                rp += e;
                colpart[nb] += e;
            }
            rp += __shfl_xor(rp, 1);
            rp += __shfl_xor(rp, 2);
            rp += __shfl_xor(rp, 4);
            rp += __shfl_xor(rp, 8);
            if (m15 == 0) atomicAdd(&rowS[vloc], rp);   // wx=0,1 waves collide
        }
    }
    // col partials: reduce over the 4 row-groups (g4), then LDS-accumulate
    #pragma unroll
    for (int nb = 0; nb < 4; ++nb) {
        float cp = colpart[nb];
        cp += __shfl_xor(cp, 16);
        cp += __shfl_xor(cp, 32);
        if (lane < 16) atomicAdd(&colS[wx * 64 + nb * 16 + lane], cp);
    }
    if (vq == tb) {   // only diagonal WGs carry diag terms
        #pragma unroll
        for (int off = 1; off < 64; off <<= 1) dsum += __shfl_xor(dsum, off);
        if (lane == 0) atomicAdd(&g_dsum[bp], dsum);
    }
    __syncthreads();
    if (tid < 128) {
        atomicAdd(&g_rowsum[(size_t)bp * 512 + vq * 128 + tid], rowS[tid]);
        atomicAdd(&g_colsum[(size_t)bp * 512 + tb * 128 + tid], colS[tid]);
    }
}

// ---------------- K3: per-(b,p) clip loss ----------------
__global__ __launch_bounds__(256) void k_clip(
    const float* __restrict__ g_rowsum, const float* __restrict__ g_colsum,
    const float* __restrict__ g_dsum, float* __restrict__ clip)
{
    __shared__ float red[4];
    int bp = blockIdx.x, tid = threadIdx.x;
    int lane = tid & 63, wave = tid >> 6;
    float s = 0.f;
    #pragma unroll
    for (int c = 0; c < 2; ++c) {
        int i = c * 256 + tid;
        s += 0.5f * (logf(g_rowsum[(size_t)bp * 512 + i]) +
                     logf(g_colsum[(size_t)bp * 512 + i]));
    }
    #pragma unroll
    for (int off = 1; off < 64; off <<= 1) s += __shfl_xor(s, off);
    if (lane == 0) red[wave] = s;
    __syncthreads();
    if (tid == 0)
        clip[bp] = (red[0] + red[1] + red[2] + red[3] - g_dsum[bp]) * (1.0f / 512.0f);
}

// ---------------- K4: loss / acc / preds ----------------
__global__ __launch_bounds__(256) void k_final(
    const float* __restrict__ clip, const float* __restrict__ output,
    float* __restrict__ out)
{
    __shared__ float cl[256], ou[256], red[4];
    __shared__ int preds[16];
    int tid = threadIdx.x, lane = tid & 63, wave = tid >> 6;
    cl[tid] = clip[tid];
    ou[tid] = output[tid];
    __syncthreads();
    float d = ou[tid] - cl[tid];
    float s = d * d;
    #pragma unroll
    for (int off = 1; off < 64; off <<= 1) s += __shfl_xor(s, off);
    if (lane == 0) red[wave] = s;
    if (tid < 16) {   // preds = argmin over output row (first occurrence)
        float m = ou[tid * 16]; int a = 0;
        for (int q = 1; q < 16; ++q)
            if (ou[tid * 16 + q] < m) { m = ou[tid * 16 + q]; a = q; }
        preds[tid] = a;
    }
    __syncthreads();
    if (tid == 0) {
        int cnt = 0;
        for (int bb = 0; bb < 16; ++bb) {
            float m = cl[bb * 16]; int a = 0;
            for (int q = 1; q < 16; ++q)
                if (cl[bb * 16 + q] < m) { m = cl[bb * 16 + q]; a = q; }
            cnt += (preds[bb] == a);
        }
        out[0] = (red[0] + red[1] + red[2] + red[3]) * (1.0f / 256.0f);
        out[1] = (float)cnt * (100.0f / 16.0f);
    }
    __syncthreads();
    for (int j = tid; j < 16 * 512; j += 256)
        out[2 + j] = (float)preds[j >> 9];
}

extern "C" void kernel_launch(void* const* d_in, const int* in_sizes, int n_in,
                              void* d_out, int out_size, void* d_ws, size_t ws_size,
                              hipStream_t stream)
{
    const float* output = (const float*)d_in[0];   // (16,16)
    const float* text   = (const float*)d_in[1];   // (16,512,16,512)
    const float* vis    = (const float*)d_in[2];   // (16,512,512)

    float* g_rowsum = (float*)d_ws;                // 256*512
    float* g_colsum = g_rowsum + 256 * 512;        // 256*512
    float* g_dsum   = g_colsum + 256 * 512;        // 256
    float* clip     = g_dsum + 256;                // 256
    float* vinv     = clip + 256;                  // 8192
    // zero rowsum + colsum + dsum (atomic accumulation targets)
    (void)hipMemsetAsync(d_ws, 0, (size_t)(2 * 256 * 512 + 256) * sizeof(float), stream);

    k_vinv <<<2048, 256, 0, stream>>>(vis, vinv);
    k_main <<<4096, 256, 0, stream>>>(vis, text, vinv, g_rowsum, g_colsum, g_dsum);
    k_clip <<<256, 256, 0, stream>>>(g_rowsum, g_colsum, g_dsum, clip);
    k_final<<<1, 256, 0, stream>>>(clip, output, (float*)d_out);
}

// Round 4
// 485.295 us; speedup vs baseline: 1.0030x; 1.0030x over previous
//
#include <hip/hip_runtime.h>

#define EPSN 1e-8f

typedef _Float16 half8 __attribute__((ext_vector_type(8)));
typedef __fp16 fp16x2 __attribute__((ext_vector_type(2)));   // cvt_pkrtz result type
typedef float floatx4 __attribute__((ext_vector_type(4)));

// lgkmcnt-only barrier: orders LDS across the workgroup without draining vmcnt.
#define LDS_BARRIER()                                              \
    do {                                                           \
        asm volatile("s_waitcnt lgkmcnt(0)" ::: "memory");         \
        __builtin_amdgcn_s_barrier();                              \
        asm volatile("" ::: "memory");                             \
    } while (0)

// global -> LDS direct DMA, 16 B per lane. LDS dest is wave-uniform base
// (+ lane*16 implicit); global src is per-lane (carries the XOR swizzle).
#define GLL16(g, l)                                                        \
    __builtin_amdgcn_global_load_lds(                                      \
        (const __attribute__((address_space(1))) unsigned int*)(g),        \
        (__attribute__((address_space(3))) unsigned int*)(l), 16, 0, 0)

// ---------------- K0: normalize + fp16 convert (one wave per row) ----------
// Replaces k_vinv + all in-loop cvt/norm work of k_main. Also deduplicates:
// previously each text tile was converted 4x (vq twins), vis 64x.
// textH layout is transposed to (b, c, s, d) so k_main's B rows for a fixed
// (b,p) are contiguous (1 KB stride).
__global__ __launch_bounds__(256) void k_prep(
    const float* __restrict__ vis, const float* __restrict__ text,
    _Float16* __restrict__ visH, _Float16* __restrict__ textH)
{
    int row  = blockIdx.x * 4 + (threadIdx.x >> 6);   // 8192 vis + 131072 text
    int lane = threadIdx.x & 63;
    const float* src;
    _Float16* dst;
    if (row < 8192) {
        src = vis + (size_t)row * 512;
        dst = visH + (size_t)row * 512;
    } else {
        int r  = row - 8192;              // flat over (b,s,c)
        int c  = r & 15;
        int s  = (r >> 4) & 511;
        int bb = r >> 13;
        src = text + (size_t)r * 512;
        dst = textH + ((size_t)(bb * 16 + c) * 512 + s) * 512;   // (b,c,s,d)
    }
    const float4* s4 = reinterpret_cast<const float4*>(src);
    float4 x = s4[lane * 2];
    float4 y = s4[lane * 2 + 1];
    float ss = x.x*x.x + x.y*x.y + x.z*x.z + x.w*x.w
             + y.x*y.x + y.y*y.y + y.z*y.z + y.w*y.w;
    #pragma unroll
    for (int off = 1; off < 64; off <<= 1) ss += __shfl_xor(ss, off);
    float rinv = 1.0f / fmaxf(sqrtf(ss), EPSN);
    union { half8 v; fp16x2 q[4]; } u;
    u.q[0] = __builtin_amdgcn_cvt_pkrtz(x.x * rinv, x.y * rinv);
    u.q[1] = __builtin_amdgcn_cvt_pkrtz(x.z * rinv, x.w * rinv);
    u.q[2] = __builtin_amdgcn_cvt_pkrtz(y.x * rinv, y.y * rinv);
    u.q[3] = __builtin_amdgcn_cvt_pkrtz(y.z * rinv, y.w * rinv);
    *reinterpret_cast<half8*>(dst + lane * 8) = u.v;
}

// ---------------- K2 (new): m97-style GEMM + exp-sums ----------------
// WG: 256 threads / 4 waves in 2x2, WG tile 128v x 128t, wave tile 64x64.
// BK=64 fp16 (128 B per row-chunk). Staging is pure global_load_lds (zero
// staging VALU/cvt in the hot loop — that overhead was ~60% of the old
// k_main's 1870 cyc/chunk vs m97's 736). LDS rows are 64 halfs, with the
// 16-B unit XOR-swizzled via the per-lane GLOBAL source address
// (unit u of row r holds global unit u ^ (r&7)); LDS dest stays linear as
// global_load_lds requires. Fragment ds_read undoes the XOR -> 2 lanes/bank
// (free, m136).
__global__ __launch_bounds__(256, 4) void k_main(
    const _Float16* __restrict__ visH, const _Float16* __restrict__ textH,
    float* __restrict__ g_rowsum, float* __restrict__ g_colsum,
    float* __restrict__ g_dsum)
{
    __shared__ _Float16 Ash[128 * 64];   // 16 KB
    __shared__ _Float16 Bsh[128 * 64];   // 16 KB
    __shared__ float rowS[128];
    __shared__ float colS[128];

    // ---- XCD swizzle: twins (same s>>2, same xcd, s&3=0..3) share text tile
    const int pid = blockIdx.x;
    const int xcd = pid & 7;
    const int s_  = pid >> 3;
    const int blk = (s_ & 3) + (xcd << 2) + ((s_ >> 2) << 5);   // bijection on 4096

    const int vq   = blk & 3;
    const int tb   = (blk >> 2) & 3;
    const int bp   = blk >> 4;            // b*16 + p
    const int b    = bp >> 4;
    const int tid  = threadIdx.x;
    const int lane = tid & 63;
    const int wave = tid >> 6;
    const int wy   = wave >> 1;           // v-half of WG tile
    const int wx   = wave & 1;            // t-half of WG tile
    const int m15  = lane & 15;
    const int g4   = lane >> 4;

    if (tid < 128) { rowS[tid] = 0.f; colS[tid] = 0.f; }

    floatx4 acc[4][4];
    floatx4 zf = {0.f, 0.f, 0.f, 0.f};
    #pragma unroll
    for (int mb = 0; mb < 4; ++mb)
        #pragma unroll
        for (int nb = 0; nb < 4; ++nb) acc[mb][nb] = zf;

    // ---- staging: wave w stages rows [w*32, w*32+32) of A and B.
    // One GLL16 covers 8 rows x 128 B; per-lane src carries the swizzle.
    const int w32 = wave * 32;
    const int lr8 = lane >> 3;            // row within 8-row group
    const int ls  = lane & 7;             // 16-B unit within row
    const int swz = ls ^ lr8;             // swizzled global unit
    const _Float16* aSrc =
        visH + ((size_t)(b * 512 + vq * 128 + w32 + lr8)) * 512 + swz * 8;
    const _Float16* bSrc =
        textH + ((size_t)(bp * 512 + tb * 128 + w32 + lr8)) * 512 + swz * 8;
    _Float16* aDst = &Ash[w32 * 64];
    _Float16* bDst = &Bsh[w32 * 64];

    for (int kc = 0; kc < 8; ++kc) {
        const int ko = kc * 64;
        #pragma unroll
        for (int i = 0; i < 4; ++i) {
            GLL16(aSrc + i * (8 * 512) + ko, aDst + i * 512);
            GLL16(bSrc + i * (8 * 512) + ko, bDst + i * 512);
        }
        asm volatile("s_waitcnt vmcnt(0)" ::: "memory");
        __builtin_amdgcn_s_barrier();
        asm volatile("" ::: "memory");
        // ---- 32 MFMA on the 64x64 wave tile, K=64 ----
        #pragma unroll
        for (int ki = 0; ki < 2; ++ki) {
            half8 af[4];
            #pragma unroll
            for (int mb = 0; mb < 4; ++mb)
                af[mb] = *reinterpret_cast<const half8*>(
                    &Ash[(wy * 64 + mb * 16 + m15) * 64 +
                         (((ki * 4 + g4) ^ (m15 & 7)) * 8)]);
            #pragma unroll
            for (int nb = 0; nb < 4; ++nb) {
                half8 bf = *reinterpret_cast<const half8*>(
                    &Bsh[(wx * 64 + nb * 16 + m15) * 64 +
                         (((ki * 4 + g4) ^ (m15 & 7)) * 8)]);
                #pragma unroll
                for (int mb = 0; mb < 4; ++mb)
                    acc[mb][nb] = __builtin_amdgcn_mfma_f32_16x16x32_f16(
                        af[mb], bf, acc[mb][nb], 0, 0, 0);
            }
        }
        LDS_BARRIER();   // reads done before next chunk's DMA writes
    }

    float colpart[4];
    #pragma unroll
    for (int nb = 0; nb < 4; ++nb) colpart[nb] = 0.f;
    float dsum = 0.f;

    // epilogue: inputs are pre-normalized, sim = acc directly
    #pragma unroll
    for (int mb = 0; mb < 4; ++mb) {
        #pragma unroll
        for (int r = 0; r < 4; ++r) {
            int vloc  = wy * 64 + mb * 16 + g4 * 4 + r;      // C/D row mapping
            int vglob = vq * 128 + vloc;
            float rp  = 0.f;
            #pragma unroll
            for (int nb = 0; nb < 4; ++nb) {
                float sim  = acc[mb][nb][r];
                int tglob  = tb * 128 + wx * 64 + nb * 16 + m15;  // C/D col mapping
                if (vglob == tglob) dsum += sim;
                float e = __expf(sim);
                rp += e;
                colpart[nb] += e;
            }
            rp += __shfl_xor(rp, 1);
            rp += __shfl_xor(rp, 2);
            rp += __shfl_xor(rp, 4);
            rp += __shfl_xor(rp, 8);
            if (m15 == 0) atomicAdd(&rowS[vloc], rp);   // wx=0,1 waves collide
        }
    }
    #pragma unroll
    for (int nb = 0; nb < 4; ++nb) {
        float cp = colpart[nb];
        cp += __shfl_xor(cp, 16);
        cp += __shfl_xor(cp, 32);
        if (lane < 16) atomicAdd(&colS[wx * 64 + nb * 16 + lane], cp);
    }
    if (vq == tb) {   // only diagonal WGs carry diag terms
        #pragma unroll
        for (int off = 1; off < 64; off <<= 1) dsum += __shfl_xor(dsum, off);
        if (lane == 0) atomicAdd(&g_dsum[bp], dsum);
    }
    __syncthreads();
    if (tid < 128) {
        atomicAdd(&g_rowsum[(size_t)bp * 512 + vq * 128 + tid], rowS[tid]);
        atomicAdd(&g_colsum[(size_t)bp * 512 + tb * 128 + tid], colS[tid]);
    }
}

// ================= LEGACY PATH (round-2 best, used if ws too small) =========
__global__ __launch_bounds__(256) void k_vinv(const float* __restrict__ vis,
                                              float* __restrict__ vinv) {
    int row  = blockIdx.x * 4 + (threadIdx.x >> 6);
    int lane = threadIdx.x & 63;
    const float4* src = reinterpret_cast<const float4*>(vis + (size_t)row * 512);
    float4 a = src[lane];
    float4 b = src[lane + 64];
    float s = a.x*a.x + a.y*a.y + a.z*a.z + a.w*a.w
            + b.x*b.x + b.y*b.y + b.z*b.z + b.w*b.w;
    #pragma unroll
    for (int off = 1; off < 64; off <<= 1) s += __shfl_xor(s, off);
    if (lane == 0) vinv[row] = 1.0f / fmaxf(sqrtf(s), EPSN);
}

#define LDA 32

__global__ __launch_bounds__(256, 4) void k_main_legacy(
    const float* __restrict__ vis, const float* __restrict__ text,
    const float* __restrict__ vinv,
    float* __restrict__ g_rowsum, float* __restrict__ g_colsum,
    float* __restrict__ g_dsum)
{
    __shared__ _Float16 Ash[128 * LDA];
    __shared__ _Float16 Bsh[128 * LDA];
    __shared__ float tn2[128];
    __shared__ float vinvS[128];
    __shared__ float rowS[128];
    __shared__ float colS[128];

    const int pid = blockIdx.x;
    const int xcd = pid & 7;
    const int s_  = pid >> 3;
    const int blk = (s_ & 3) + (xcd << 2) + ((s_ >> 2) << 5);

    const int vq   = blk & 3;
    const int tb   = (blk >> 2) & 3;
    const int bp   = blk >> 4;
    const int p    = bp & 15;
    const int b    = bp >> 4;
    const int tid  = threadIdx.x;
    const int lane = tid & 63;
    const int wave = tid >> 6;
    const int wy   = wave >> 1;
    const int wx   = wave & 1;
    const int m15  = lane & 15;
    const int g4   = lane >> 4;

    if (tid < 128) {
        rowS[tid] = 0.f; colS[tid] = 0.f;
        vinvS[tid] = vinv[b * 512 + vq * 128 + tid];
    }

    floatx4 acc[4][4];
    floatx4 zf = {0.f, 0.f, 0.f, 0.f};
    #pragma unroll
    for (int mb = 0; mb < 4; ++mb)
        #pragma unroll
        for (int nb = 0; nb < 4; ++nb) acc[mb][nb] = zf;

    const int srow = tid >> 1;
    const int sko  = (tid & 1) * 16;
    const int xw  = (srow >> 1) & 3;
    const int s0  = (tid & 1) * 2;
    const int wo0 = srow * LDA + (((s0)     ^ xw) << 3);
    const int wo1 = srow * LDA + (((s0 + 1) ^ xw) << 3);
    const int koff = ((g4 ^ ((m15 >> 1) & 3)) << 3);

    const float* aPtr =
        vis + (size_t)b * 512 * 512 + (size_t)(vq * 128 + srow) * 512 + sko;
    const float* bPtr =
        text + ((size_t)((b * 512 + tb * 128 + srow) * 16 + p)) * 512 + sko;

    float tsq = 0.f;

    for (int kc = 0; kc < 16; ++kc) {
        float4 a0 = *reinterpret_cast<const float4*>(aPtr);
        float4 a1 = *reinterpret_cast<const float4*>(aPtr + 4);
        float4 a2 = *reinterpret_cast<const float4*>(aPtr + 8);
        float4 a3 = *reinterpret_cast<const float4*>(aPtr + 12);
        float4 b0 = *reinterpret_cast<const float4*>(bPtr);
        float4 b1 = *reinterpret_cast<const float4*>(bPtr + 4);
        float4 b2 = *reinterpret_cast<const float4*>(bPtr + 8);
        float4 b3 = *reinterpret_cast<const float4*>(bPtr + 12);
        aPtr += 32; bPtr += 32;

        {
            union { half8 v; fp16x2 q[4]; } u;
            u.q[0] = __builtin_amdgcn_cvt_pkrtz(a0.x, a0.y);
            u.q[1] = __builtin_amdgcn_cvt_pkrtz(a0.z, a0.w);
            u.q[2] = __builtin_amdgcn_cvt_pkrtz(a1.x, a1.y);
            u.q[3] = __builtin_amdgcn_cvt_pkrtz(a1.z, a1.w);
            *reinterpret_cast<half8*>(&Ash[wo0]) = u.v;
            u.q[0] = __builtin_amdgcn_cvt_pkrtz(a2.x, a2.y);
            u.q[1] = __builtin_amdgcn_cvt_pkrtz(a2.z, a2.w);
            u.q[2] = __builtin_amdgcn_cvt_pkrtz(a3.x, a3.y);
            u.q[3] = __builtin_amdgcn_cvt_pkrtz(a3.z, a3.w);
            *reinterpret_cast<half8*>(&Ash[wo1]) = u.v;
        }
        tsq += b0.x*b0.x + b0.y*b0.y + b0.z*b0.z + b0.w*b0.w
             + b1.x*b1.x + b1.y*b1.y + b1.z*b1.z + b1.w*b1.w
             + b2.x*b2.x + b2.y*b2.y + b2.z*b2.z + b2.w*b2.w
             + b3.x*b3.x + b3.y*b3.y + b3.z*b3.z + b3.w*b3.w;
        {
            union { half8 v; fp16x2 q[4]; } u;
            u.q[0] = __builtin_amdgcn_cvt_pkrtz(b0.x, b0.y);
            u.q[1] = __builtin_amdgcn_cvt_pkrtz(b0.z, b0.w);
            u.q[2] = __builtin_amdgcn_cvt_pkrtz(b1.x, b1.y);
            u.q[3] = __builtin_amdgcn_cvt_pkrtz(b1.z, b1.w);
            *reinterpret_cast<half8*>(&Bsh[wo0]) = u.v;
            u.q[0] = __builtin_amdgcn_cvt_pkrtz(b2.x, b2.y);
            u.q[1] = __builtin_amdgcn_cvt_pkrtz(b2.z, b2.w);
            u.q[2] = __builtin_amdgcn_cvt_pkrtz(b3.x, b3.y);
            u.q[3] = __builtin_amdgcn_cvt_pkrtz(b3.z, b3.w);
            *reinterpret_cast<half8*>(&Bsh[wo1]) = u.v;
        }
        LDS_BARRIER();
        half8 af[4];
        #pragma unroll
        for (int mb = 0; mb < 4; ++mb)
            af[mb] = *reinterpret_cast<const half8*>(
                &Ash[(wy * 64 + mb * 16 + m15) * LDA + koff]);
        #pragma unroll
        for (int nb = 0; nb < 4; ++nb) {
            half8 bf = *reinterpret_cast<const half8*>(
                &Bsh[(wx * 64 + nb * 16 + m15) * LDA + koff]);
            #pragma unroll
            for (int mb = 0; mb < 4; ++mb)
                acc[mb][nb] = __builtin_amdgcn_mfma_f32_16x16x32_f16(
                    af[mb], bf, acc[mb][nb], 0, 0, 0);
        }
        LDS_BARRIER();
    }

    tsq += __shfl_xor(tsq, 1);
    if ((tid & 1) == 0)
        tn2[srow] = 1.0f / fmaxf(sqrtf(tsq), EPSN);
    __syncthreads();

    float tinvc[4];
    #pragma unroll
    for (int nb = 0; nb < 4; ++nb) tinvc[nb] = tn2[wx * 64 + nb * 16 + m15];

    float colpart[4];
    #pragma unroll
    for (int nb = 0; nb < 4; ++nb) colpart[nb] = 0.f;
    float dsum = 0.f;

    #pragma unroll
    for (int mb = 0; mb < 4; ++mb) {
        #pragma unroll
        for (int r = 0; r < 4; ++r) {
            int vloc  = wy * 64 + mb * 16 + g4 * 4 + r;
            int vglob = vq * 128 + vloc;
            float vi  = vinvS[vloc];
            float rp  = 0.f;
            #pragma unroll
            for (int nb = 0; nb < 4; ++nb) {
                float sim  = acc[mb][nb][r] * vi * tinvc[nb];
                int tglob  = tb * 128 + wx * 64 + nb * 16 + m15;
                if (vglob == tglob) dsum += sim;
                float e = __expf(sim);
                rp += e;
                colpart[nb] += e;
            }
            rp += __shfl_xor(rp, 1);
            rp += __shfl_xor(rp, 2);
            rp += __shfl_xor(rp, 4);
            rp += __shfl_xor(rp, 8);
            if (m15 == 0) atomicAdd(&rowS[vloc], rp);
        }
    }
    #pragma unroll
    for (int nb = 0; nb < 4; ++nb) {
        float cp = colpart[nb];
        cp += __shfl_xor(cp, 16);
        cp += __shfl_xor(cp, 32);
        if (lane < 16) atomicAdd(&colS[wx * 64 + nb * 16 + lane], cp);
    }
    if (vq == tb) {
        #pragma unroll
        for (int off = 1; off < 64; off <<= 1) dsum += __shfl_xor(dsum, off);
        if (lane == 0) atomicAdd(&g_dsum[bp], dsum);
    }
    __syncthreads();
    if (tid < 128) {
        atomicAdd(&g_rowsum[(size_t)bp * 512 + vq * 128 + tid], rowS[tid]);
        atomicAdd(&g_colsum[(size_t)bp * 512 + tb * 128 + tid], colS[tid]);
    }
}

// ---------------- K3: per-(b,p) clip loss ----------------
__global__ __launch_bounds__(256) void k_clip(
    const float* __restrict__ g_rowsum, const float* __restrict__ g_colsum,
    const float* __restrict__ g_dsum, float* __restrict__ clip)
{
    __shared__ float red[4];
    int bp = blockIdx.x, tid = threadIdx.x;
    int lane = tid & 63, wave = tid >> 6;
    float s = 0.f;
    #pragma unroll
    for (int c = 0; c < 2; ++c) {
        int i = c * 256 + tid;
        s += 0.5f * (logf(g_rowsum[(size_t)bp * 512 + i]) +
                     logf(g_colsum[(size_t)bp * 512 + i]));
    }
    #pragma unroll
    for (int off = 1; off < 64; off <<= 1) s += __shfl_xor(s, off);
    if (lane == 0) red[wave] = s;
    __syncthreads();
    if (tid == 0)
        clip[bp] = (red[0] + red[1] + red[2] + red[3] - g_dsum[bp]) * (1.0f / 512.0f);
}

// ---------------- K4: loss / acc / preds ----------------
__global__ __launch_bounds__(256) void k_final(
    const float* __restrict__ clip, const float* __restrict__ output,
    float* __restrict__ out)
{
    __shared__ float cl[256], ou[256], red[4];
    __shared__ int preds[16];
    int tid = threadIdx.x, lane = tid & 63, wave = tid >> 6;
    cl[tid] = clip[tid];
    ou[tid] = output[tid];
    __syncthreads();
    float d = ou[tid] - cl[tid];
    float s = d * d;
    #pragma unroll
    for (int off = 1; off < 64; off <<= 1) s += __shfl_xor(s, off);
    if (lane == 0) red[wave] = s;
    if (tid < 16) {
        float m = ou[tid * 16]; int a = 0;
        for (int q = 1; q < 16; ++q)
            if (ou[tid * 16 + q] < m) { m = ou[tid * 16 + q]; a = q; }
        preds[tid] = a;
    }
    __syncthreads();
    if (tid == 0) {
        int cnt = 0;
        for (int bb = 0; bb < 16; ++bb) {
            float m = cl[bb * 16]; int a = 0;
            for (int q = 1; q < 16; ++q)
                if (cl[bb * 16 + q] < m) { m = cl[bb * 16 + q]; a = q; }
            cnt += (preds[bb] == a);
        }
        out[0] = (red[0] + red[1] + red[2] + red[3]) * (1.0f / 256.0f);
        out[1] = (float)cnt * (100.0f / 16.0f);
    }
    __syncthreads();
    for (int j = tid; j < 16 * 512; j += 256)
        out[2 + j] = (float)preds[j >> 9];
}

extern "C" void kernel_launch(void* const* d_in, const int* in_sizes, int n_in,
                              void* d_out, int out_size, void* d_ws, size_t ws_size,
                              hipStream_t stream)
{
    const float* output = (const float*)d_in[0];   // (16,16)
    const float* text   = (const float*)d_in[1];   // (16,512,16,512)
    const float* vis    = (const float*)d_in[2];   // (16,512,512)

    float* g_rowsum = (float*)d_ws;                // 256*512
    float* g_colsum = g_rowsum + 256 * 512;        // 256*512
    float* g_dsum   = g_colsum + 256 * 512;        // 256
    float* clip     = g_dsum + 256;                // 256
    float* vinv     = clip + 256;                  // 8192 (legacy path)
    _Float16* visH  = (_Float16*)(vinv + 8192);            // 16*512*512 halfs
    _Float16* textH = visH + (size_t)8192 * 512;           // 16*16*512*512 halfs
    size_t need = (size_t)((char*)(textH + (size_t)131072 * 512) - (char*)d_ws);

    // zero rowsum + colsum + dsum (atomic accumulation targets)
    (void)hipMemsetAsync(d_ws, 0, (size_t)(2 * 256 * 512 + 256) * sizeof(float), stream);

    if (ws_size >= need) {
        k_prep<<<(8192 + 131072) / 4, 256, 0, stream>>>(vis, text, visH, textH);
        k_main<<<4096, 256, 0, stream>>>(visH, textH, g_rowsum, g_colsum, g_dsum);
    } else {
        k_vinv<<<2048, 256, 0, stream>>>(vis, vinv);
        k_main_legacy<<<4096, 256, 0, stream>>>(vis, text, vinv,
                                                g_rowsum, g_colsum, g_dsum);
    }
    k_clip <<<256, 256, 0, stream>>>(g_rowsum, g_colsum, g_dsum, clip);
    k_final<<<1, 256, 0, stream>>>(clip, output, (float*)d_out);
}